// Round 3
// baseline (11999.099 us; speedup 1.0000x reference)
//
#include <hip/hip_runtime.h>
#include <math.h>

// Problem constants (match reference)
constexpr int T  = 512;
constexpr int B  = 64;
constexpr int I  = 1024;   // input width for BOTH layers (layer1 input = 2*H = 1024)
constexpr int H  = 512;
constexpr int M  = T * B;  // 32768 GEMM rows

// ---------------------------------------------------------------------------
// xproj GEMM:  P_c[row, h] = sum_i X[row,i] * nin_c[row%B, i] * Wih_c[h,i]  + bih_c[h]
// A (M x K) row-major, W (H x K) row-major (NT gemm). 128x128 tile, BK=32,
// 256 threads, 8x8 register block per thread.
// grid = (M/128, H/128, 2 cells)
// ---------------------------------------------------------------------------
#define BM 128
#define BN 128
#define BK 32
#define LDP 132  // padded leading dim for LDS tiles (128+4, keeps 16B alignment)

__global__ __launch_bounds__(256) void gemm_xproj(
    const float* __restrict__ X,     // (M, 1024)
    const float* __restrict__ nin,   // (2, B, 1024)  (layer base)
    const float* __restrict__ wih,   // (2, H, 1024)
    const float* __restrict__ bih,   // (2, H)
    float* __restrict__ P)           // (2, M, H)
{
    const int cell = blockIdx.z;
    const int bm = blockIdx.x;
    const int bn = blockIdx.y;

    const float* Wc = wih + (size_t)cell * H * I;
    const float* Nc = nin + (size_t)cell * B * I;
    const float* bc = bih + (size_t)cell * H;
    float* Pc       = P   + (size_t)cell * M * H;

    __shared__ float As[BK][LDP];
    __shared__ float Bs[BK][LDP];

    const int tid = threadIdx.x;
    const int tx = tid % 16;          // n direction (8 cols each)
    const int ty = tid / 16;          // m direction (8 rows each)

    float acc[8][8];
#pragma unroll
    for (int i = 0; i < 8; ++i)
#pragma unroll
        for (int j = 0; j < 8; ++j) acc[i][j] = 0.f;

    const int kq    = (tid % 8) * 4;  // k offset of this thread's float4
    const int rbase = tid / 8;        // 0..31 row within a 32-row pass

    for (int k0 = 0; k0 < I; k0 += BK) {
        // ---- load A tile (128 rows x 32 k), noise fused ----
#pragma unroll
        for (int p = 0; p < 4; ++p) {
            const int row_l = p * 32 + rbase;
            const int grow  = bm * BM + row_l;
            float4 a = *(const float4*)&X[(size_t)grow * I + k0 + kq];
            float4 nn = *(const float4*)&Nc[(size_t)(grow & (B - 1)) * I + k0 + kq];
            a.x *= nn.x; a.y *= nn.y; a.z *= nn.z; a.w *= nn.w;
            As[kq + 0][row_l] = a.x;
            As[kq + 1][row_l] = a.y;
            As[kq + 2][row_l] = a.z;
            As[kq + 3][row_l] = a.w;
        }
        // ---- load B tile (128 h-rows x 32 k) ----
#pragma unroll
        for (int p = 0; p < 4; ++p) {
            const int hrow = p * 32 + rbase;
            float4 w = *(const float4*)&Wc[(size_t)(bn * BN + hrow) * I + k0 + kq];
            Bs[kq + 0][hrow] = w.x;
            Bs[kq + 1][hrow] = w.y;
            Bs[kq + 2][hrow] = w.z;
            Bs[kq + 3][hrow] = w.w;
        }
        __syncthreads();

#pragma unroll
        for (int k = 0; k < BK; ++k) {
            float a[8], b[8];
            *(float4*)&a[0] = *(const float4*)&As[k][ty * 8];
            *(float4*)&a[4] = *(const float4*)&As[k][ty * 8 + 4];
            *(float4*)&b[0] = *(const float4*)&Bs[k][tx * 8];
            *(float4*)&b[4] = *(const float4*)&Bs[k][tx * 8 + 4];
#pragma unroll
            for (int i = 0; i < 8; ++i)
#pragma unroll
                for (int j = 0; j < 8; ++j)
                    acc[i][j] = fmaf(a[i], b[j], acc[i][j]);
        }
        __syncthreads();
    }

    // ---- epilogue: add bias, store ----
    const int grow0 = bm * BM + ty * 8;
    const int gcol0 = bn * BN + tx * 8;
    float bb[8];
#pragma unroll
    for (int j = 0; j < 8; ++j) bb[j] = bc[gcol0 + j];
#pragma unroll
    for (int i = 0; i < 8; ++i) {
        float4 o0, o1;
        o0.x = acc[i][0] + bb[0]; o0.y = acc[i][1] + bb[1];
        o0.z = acc[i][2] + bb[2]; o0.w = acc[i][3] + bb[3];
        o1.x = acc[i][4] + bb[4]; o1.y = acc[i][5] + bb[5];
        o1.z = acc[i][6] + bb[6]; o1.w = acc[i][7] + bb[7];
        *(float4*)&Pc[(size_t)(grow0 + i) * H + gcol0]     = o0;
        *(float4*)&Pc[(size_t)(grow0 + i) * H + gcol0 + 4] = o1;
    }
}

// ---------------------------------------------------------------------------
// Recurrent scan. One launch per layer. grid = (32 WGs x 2 directions),
// 512 threads. Each WG owns 2 batch rows for the entire time loop (batch
// rows are independent -> no cross-WG sync). h/u state in LDS.
// Phase 1 (matvec): thread (q = tid&3, jl = tid>>2) accumulates j = q*128+jl
// over i-segment q; quad butterfly-reduce publishes to LDS.
// Phase 2: thread (row2 = tid>>8, j2 = tid&255) does xp + bias + tanh + mask
// blend for j2 and j2+256, updates h/u, writes ys.
// ---------------------------------------------------------------------------
__global__ __launch_bounds__(512) void rnn_scan(
    const float* __restrict__ P,     // (2, T*B, H) xproj for this layer
    const float* __restrict__ mask,  // (T, B)
    const float* __restrict__ whh,   // (2, H, H) layer base
    const float* __restrict__ bhh,   // (2, H)
    const float* __restrict__ nh,    // (2, B, H)
    float* __restrict__ Y,           // (T, B, 2H) output x of this layer
    float* __restrict__ hn)          // (2, B, H) at this layer's offset
{
    const int d  = blockIdx.y;
    const int wg = blockIdx.x;       // 0..31
    const int r0 = wg * 2;           // batch rows r0, r0+1

    const float* Wc  = whh + (size_t)d * H * H;
    const float* Pc  = P   + (size_t)d * M * H;
    const float* nhc = nh  + (size_t)d * B * H;
    const float* bc  = bhh + (size_t)d * H;

    __shared__ float hsm[2][H];
    __shared__ float usm[2][H];
    __shared__ float pre[2][H];

    const int tid = threadIdx.x;
    for (int i = tid; i < 2 * H; i += 512) {
        ((float*)hsm)[i] = 0.f;
        ((float*)usm)[i] = 0.f;
    }
    __syncthreads();

    const int q  = tid & 3;
    const int jl = tid >> 2;          // 0..127
    const int row2 = tid >> 8;        // 0..1
    const int j2   = tid & 255;       // 0..255

    const float nh0 = nhc[(size_t)(r0 + row2) * H + j2];
    const float nh1 = nhc[(size_t)(r0 + row2) * H + j2 + 256];
    const float bb0 = bc[j2];
    const float bb1 = bc[j2 + 256];

    const int t0 = (d == 0) ? 0 : T - 1;
    const int dt = (d == 0) ? 1 : -1;

    for (int s = 0; s < T; ++s) {
        const int t = t0 + dt * s;

        // ---- phase 1: pre[r][j] = sum_i Whh[j,i] * u[r][i] ----
        float a00 = 0.f, a01 = 0.f, a10 = 0.f, a11 = 0.f,
              a20 = 0.f, a21 = 0.f, a30 = 0.f, a31 = 0.f;
#pragma unroll 4
        for (int kk = 0; kk < 32; ++kk) {
            const int ib = kk * 16 + q * 4;
            const float4 u0 = *(const float4*)&usm[0][ib];
            const float4 u1 = *(const float4*)&usm[1][ib];
            const float4 w0 = *(const float4*)&Wc[(size_t)(0 * 128 + jl) * H + ib];
            const float4 w1 = *(const float4*)&Wc[(size_t)(1 * 128 + jl) * H + ib];
            const float4 w2 = *(const float4*)&Wc[(size_t)(2 * 128 + jl) * H + ib];
            const float4 w3 = *(const float4*)&Wc[(size_t)(3 * 128 + jl) * H + ib];
            a00 += w0.x*u0.x + w0.y*u0.y + w0.z*u0.z + w0.w*u0.w;
            a01 += w0.x*u1.x + w0.y*u1.y + w0.z*u1.z + w0.w*u1.w;
            a10 += w1.x*u0.x + w1.y*u0.y + w1.z*u0.z + w1.w*u0.w;
            a11 += w1.x*u1.x + w1.y*u1.y + w1.z*u1.z + w1.w*u1.w;
            a20 += w2.x*u0.x + w2.y*u0.y + w2.z*u0.z + w2.w*u0.w;
            a21 += w2.x*u1.x + w2.y*u1.y + w2.z*u1.z + w2.w*u1.w;
            a30 += w3.x*u0.x + w3.y*u0.y + w3.z*u0.z + w3.w*u0.w;
            a31 += w3.x*u1.x + w3.y*u1.y + w3.z*u1.z + w3.w*u1.w;
        }
        // quad butterfly (lanes sharing jl differ only in q = lane&3)
        a00 += __shfl_xor(a00, 1); a00 += __shfl_xor(a00, 2);
        a01 += __shfl_xor(a01, 1); a01 += __shfl_xor(a01, 2);
        a10 += __shfl_xor(a10, 1); a10 += __shfl_xor(a10, 2);
        a11 += __shfl_xor(a11, 1); a11 += __shfl_xor(a11, 2);
        a20 += __shfl_xor(a20, 1); a20 += __shfl_xor(a20, 2);
        a21 += __shfl_xor(a21, 1); a21 += __shfl_xor(a21, 2);
        a30 += __shfl_xor(a30, 1); a30 += __shfl_xor(a30, 2);
        a31 += __shfl_xor(a31, 1); a31 += __shfl_xor(a31, 2);
        // lane q publishes j = q*128 + jl
        const float s0 = (q == 0) ? a00 : (q == 1) ? a10 : (q == 2) ? a20 : a30;
        const float s1 = (q == 0) ? a01 : (q == 1) ? a11 : (q == 2) ? a21 : a31;
        const int jw = q * 128 + jl;
        pre[0][jw] = s0;
        pre[1][jw] = s1;
        __syncthreads();

        // ---- phase 2: activation + mask blend + state update ----
        const float m = mask[(size_t)t * B + r0 + row2];
        const size_t prow = ((size_t)t * B + r0 + row2) * (size_t)H;
        const size_t yrow = ((size_t)t * B + r0 + row2) * (size_t)(2 * H) + (size_t)d * H;
        {
            const float hp   = pre[row2][j2] + Pc[prow + j2] + bb0;
            const float th   = tanhf(hp);
            const float hold = hsm[row2][j2];
            const float h2   = th * m + hold * (1.f - m);
            hsm[row2][j2] = h2;
            usm[row2][j2] = h2 * nh0;
            Y[yrow + j2]  = h2;
        }
        {
            const float hp   = pre[row2][j2 + 256] + Pc[prow + j2 + 256] + bb1;
            const float th   = tanhf(hp);
            const float hold = hsm[row2][j2 + 256];
            const float h2   = th * m + hold * (1.f - m);
            hsm[row2][j2 + 256] = h2;
            usm[row2][j2 + 256] = h2 * nh1;
            Y[yrow + j2 + 256]  = h2;
        }
        __syncthreads();
    }

    // final hidden state
    hn[((size_t)d * B + r0 + row2) * H + j2]       = hsm[row2][j2];
    hn[((size_t)d * B + r0 + row2) * H + j2 + 256] = hsm[row2][j2 + 256];
}

// ---------------------------------------------------------------------------
extern "C" void kernel_launch(void* const* d_in, const int* in_sizes, int n_in,
                              void* d_out, int out_size, void* d_ws, size_t ws_size,
                              hipStream_t stream) {
    const float* input = (const float*)d_in[0];  // (T,B,I)
    const float* mask  = (const float*)d_in[1];  // (T,B)
    const float* w_ih  = (const float*)d_in[2];  // (4,H,I)
    const float* w_hh  = (const float*)d_in[3];  // (4,H,H)
    const float* b_ih  = (const float*)d_in[4];  // (4,H)
    const float* b_hh  = (const float*)d_in[5];  // (4,H)
    const float* p_nin = (const float*)d_in[6];  // (4,B,I)
    const float* p_nh  = (const float*)d_in[7];  // (4,B,H)

    float* out_x  = (float*)d_out;                        // (T,B,2H)
    float* out_hn = out_x + (size_t)T * B * (2 * H);      // (4,B,H)
    float* P      = (float*)d_ws;                         // (2, M, H) = 128 MB

    for (int layer = 0; layer < 2; ++layer) {
        const float* X = (layer == 0) ? input : out_x;
        const int cb = layer * 2;
        gemm_xproj<<<dim3(M / BM, H / BN, 2), 256, 0, stream>>>(
            X,
            p_nin + (size_t)cb * B * I,
            w_ih + (size_t)cb * H * I,
            b_ih + (size_t)cb * H,
            P);
        rnn_scan<<<dim3(32, 2), 512, 0, stream>>>(
            P, mask,
            w_hh + (size_t)cb * H * H,
            b_hh + (size_t)cb * H,
            p_nh + (size_t)cb * B * H,
            out_x,
            out_hn + (size_t)cb * B * H);
    }
}